// Round 1
// baseline (355.031 us; speedup 1.0000x reference)
//
#include <hip/hip_runtime.h>
#include <math.h>

#define NB 4
#define NC 64
#define NN 4096
#define NH 4

// ---------- top-5 insertion helpers (all static indexing) ----------
__device__ __forceinline__ void ins5(float (&tv)[5], int (&ti)[5], float v, int m) {
    // strict > : equal values keep earlier (smaller) index, candidates arrive in ascending m
    if (v > tv[4]) {
        if (v > tv[3]) {
            tv[4]=tv[3]; ti[4]=ti[3];
            if (v > tv[2]) {
                tv[3]=tv[2]; ti[3]=ti[2];
                if (v > tv[1]) {
                    tv[2]=tv[1]; ti[2]=ti[1];
                    if (v > tv[0]) { tv[1]=tv[0]; ti[1]=ti[0]; tv[0]=v; ti[0]=m; }
                    else          { tv[1]=v; ti[1]=m; }
                } else { tv[2]=v; ti[2]=m; }
            } else { tv[3]=v; ti[3]=m; }
        } else { tv[4]=v; ti[4]=m; }
    }
}

__device__ __forceinline__ bool gtt(float v, int m, float v2, int m2) {
    return (v > v2) || ((v == v2) && (m < m2));
}

__device__ __forceinline__ void ins5t(float (&tv)[5], int (&ti)[5], float v, int m) {
    if (gtt(v,m,tv[4],ti[4])) {
        if (gtt(v,m,tv[3],ti[3])) {
            tv[4]=tv[3]; ti[4]=ti[3];
            if (gtt(v,m,tv[2],ti[2])) {
                tv[3]=tv[2]; ti[3]=ti[2];
                if (gtt(v,m,tv[1],ti[1])) {
                    tv[2]=tv[1]; ti[2]=ti[1];
                    if (gtt(v,m,tv[0],ti[0])) { tv[1]=tv[0]; ti[1]=ti[0]; tv[0]=v; ti[0]=m; }
                    else { tv[1]=v; ti[1]=m; }
                } else { tv[2]=v; ti[2]=m; }
            } else { tv[3]=v; ti[3]=m; }
        } else { tv[4]=v; ti[4]=m; }
    }
}

// ---------- K1: channel-l2-normalize x -> xn (b,c,n) ----------
__global__ __launch_bounds__(256) void k_xnorm(const float* __restrict__ x, float* __restrict__ xn) {
    int t = blockIdx.x*256 + threadIdx.x;        // (b,n)
    int b = t >> 12, n = t & (NN-1);
    const float* xb = x + (size_t)b*NC*NN + n;
    float vals[64];
    float ss = 0.f;
    #pragma unroll
    for (int c = 0; c < NC; ++c) { vals[c] = xb[(size_t)c*NN]; ss += vals[c]*vals[c]; }
    float rn = 1.f / fmaxf(sqrtf(ss), 1e-12f);
    float* xo = xn + (size_t)b*NC*NN + n;
    #pragma unroll
    for (int c = 0; c < NC; ++c) xo[(size_t)c*NN] = vals[c]*rn;
}

// ---------- K2: q/k/v projections; output layout (b,h,n,f), f contiguous ----------
__global__ __launch_bounds__(256) void k_qkv(
    const float* __restrict__ x,
    const float* __restrict__ wk, const float* __restrict__ bk,
    const float* __restrict__ wq, const float* __restrict__ bq,
    const float* __restrict__ wv, const float* __restrict__ bv,
    float* __restrict__ qo, float* __restrict__ ko, float* __restrict__ vo)
{
    int blk = blockIdx.x;
    int nt  = blk & 63;
    int rem = blk >> 6;          // 0..47
    int ot  = rem % 12;
    int b   = rem / 12;
    int mat = ot >> 2, h = ot & 3;
    const float* w    = (mat==0) ? wk : ((mat==1) ? wq : wv);
    const float* bias = (mat==0) ? bk : ((mat==1) ? bq : bv);
    float* outp       = (mat==0) ? ko : ((mat==1) ? qo : vo);

    __shared__ __align__(16) float As[64*68];   // [c][f]
    __shared__ __align__(16) float Bs[64*68];   // [c][nl]
    int t = threadIdx.x;
    int n0 = nt*64;
    {   // stage transposed weight tile
        int f = t >> 2, q4 = t & 3;
        #pragma unroll
        for (int s = 0; s < 4; ++s) {
            int c0 = q4*16 + s*4;
            float4 w4 = *(const float4*)(w + (size_t)(h*64+f)*64 + c0);
            As[(c0+0)*68+f] = w4.x; As[(c0+1)*68+f] = w4.y;
            As[(c0+2)*68+f] = w4.z; As[(c0+3)*68+f] = w4.w;
        }
    }
    {   // stage x tile
        int u = t & 15, cb = t >> 4;
        #pragma unroll
        for (int s = 0; s < 4; ++s) {
            int c = cb + 16*s;
            float4 x4 = *(const float4*)(x + ((size_t)b*NC + c)*NN + n0 + u*4);
            *(float4*)&Bs[c*68 + u*4] = x4;
        }
    }
    __syncthreads();
    int tr = t >> 4, tc = t & 15;
    float acc[4][4];
    #pragma unroll
    for (int i=0;i<4;++i) {
        float bb = bias[h*64 + tr*4 + i];
        #pragma unroll
        for (int j=0;j<4;++j) acc[i][j] = bb;
    }
    #pragma unroll 8
    for (int c = 0; c < 64; ++c) {
        float4 a4 = *(const float4*)&As[c*68 + tr*4];
        float4 b4 = *(const float4*)&Bs[c*68 + tc*4];
        float av[4]  = {a4.x,a4.y,a4.z,a4.w};
        float bvv[4] = {b4.x,b4.y,b4.z,b4.w};
        #pragma unroll
        for (int i=0;i<4;++i)
            #pragma unroll
            for (int j=0;j<4;++j)
                acc[i][j] += av[i]*bvv[j];
    }
    float* ob = outp + (((size_t)(b*NH + h))*NN + n0)*64;
    #pragma unroll
    for (int j=0;j<4;++j) {
        float4 o4 = make_float4(acc[0][j], acc[1][j], acc[2][j], acc[3][j]);
        *(float4*)(ob + (size_t)(tc*4+j)*64 + tr*4) = o4;   // [n][f], f contiguous
    }
}

// ---------- K2b: in-place l2norm over f for q and k ----------
__global__ __launch_bounds__(256) void k_l2norm(float* __restrict__ qo, float* __restrict__ ko) {
    int t = blockIdx.x*256 + threadIdx.x;        // 0..131071
    float* base = ((t & 65536) ? ko : qo) + (size_t)(t & 65535)*64;
    float4 vb[16];
    float ss = 0.f;
    #pragma unroll
    for (int i = 0; i < 16; ++i) {
        vb[i] = *(const float4*)(base + i*4);
        ss += vb[i].x*vb[i].x + vb[i].y*vb[i].y + vb[i].z*vb[i].z + vb[i].w*vb[i].w;
    }
    float rn = 1.f / fmaxf(sqrtf(ss), 1e-12f);
    #pragma unroll
    for (int i = 0; i < 16; ++i) {
        vb[i].x*=rn; vb[i].y*=rn; vb[i].z*=rn; vb[i].w*=rn;
        *(float4*)(base + i*4) = vb[i];
    }
}

// ---------- K3: fused sim GEMM + per-row top-5 (128 rows x 2048 cols per block) ----------
#define W3 132
__global__ __launch_bounds__(256) void k_topk(const float* __restrict__ xn,
                                              float* __restrict__ pv, int* __restrict__ pi)
{
    __shared__ __align__(16) float smem[20480];  // 80 KB: As|Bs during compute, merge buffer after
    float* As = smem;             // 64*132 = 8448 floats
    float* Bs = smem + 8448;
    int blk = blockIdx.x;
    int half = blk & 1;
    int rt = (blk >> 1) & 31;
    int b  = blk >> 6;
    int rowbase = rt*128;
    int colbase = half*2048;
    const float* xb = xn + (size_t)b*NC*NN;
    int t = threadIdx.x;
    {   // A tile (this block's 128 row-vectors), loaded once
        int u = t & 31, cb = t >> 5;
        #pragma unroll
        for (int s = 0; s < 8; ++s) {
            int c = cb + 8*s;
            float4 v4 = *(const float4*)(xb + (size_t)c*NN + rowbase + u*4);
            *(float4*)&As[c*W3 + u*4] = v4;
        }
    }
    int tr = t >> 4, tc = t & 15;
    float tv[8][5]; int ti[8][5];
    #pragma unroll
    for (int i=0;i<8;++i) {
        #pragma unroll
        for (int kk=0;kk<5;++kk) { tv[i][kk] = -3.0e38f; ti[i][kk] = 0x7fffffff; }
    }
    for (int step = 0; step < 16; ++step) {
        int m0 = colbase + step*128;
        __syncthreads();
        {
            int u = t & 31, cb = t >> 5;
            #pragma unroll
            for (int s = 0; s < 8; ++s) {
                int c = cb + 8*s;
                float4 v4 = *(const float4*)(xb + (size_t)c*NN + m0 + u*4);
                *(float4*)&Bs[c*W3 + u*4] = v4;
            }
        }
        __syncthreads();
        float acc[8][8];
        #pragma unroll
        for (int i=0;i<8;++i)
            #pragma unroll
            for (int j=0;j<8;++j) acc[i][j] = 0.f;
        #pragma unroll 4
        for (int c = 0; c < 64; ++c) {
            float4 a0 = *(const float4*)&As[c*W3 + tr*8];
            float4 a1 = *(const float4*)&As[c*W3 + tr*8 + 4];
            float4 b0 = *(const float4*)&Bs[c*W3 + tc*8];
            float4 b1 = *(const float4*)&Bs[c*W3 + tc*8 + 4];
            float av[8]  = {a0.x,a0.y,a0.z,a0.w,a1.x,a1.y,a1.z,a1.w};
            float bvv[8] = {b0.x,b0.y,b0.z,b0.w,b1.x,b1.y,b1.z,b1.w};
            #pragma unroll
            for (int i=0;i<8;++i)
                #pragma unroll
                for (int j=0;j<8;++j)
                    acc[i][j] += av[i]*bvv[j];
        }
        #pragma unroll
        for (int i=0;i<8;++i)
            #pragma unroll
            for (int j=0;j<8;++j)
                ins5(tv[i], ti[i], acc[i][j], m0 + tc*8 + j);
    }
    __syncthreads();
    // dump per-(row, tc) lists into LDS
    #pragma unroll
    for (int i=0;i<8;++i) {
        int r = tr*8 + i;
        #pragma unroll
        for (int kk=0;kk<5;++kk) {
            smem[(r*16 + tc)*5 + kk]         = tv[i][kk];
            smem[10240 + (r*16 + tc)*5 + kk] = __int_as_float(ti[i][kk]);
        }
    }
    __syncthreads();
    if (t < 128) {   // per-row merge of 16 lists -> half-top5 partial
        float bv5[5]; int bi5[5];
        #pragma unroll
        for (int kk=0;kk<5;++kk) { bv5[kk] = -3.0e38f; bi5[kk] = 0x7fffffff; }
        for (int e = 0; e < 80; ++e)
            ins5t(bv5, bi5, smem[t*80 + e], __float_as_int(smem[10240 + t*80 + e]));
        size_t base = ((size_t)b*NN + rowbase + t)*10 + (size_t)half*5;
        #pragma unroll
        for (int kk=0;kk<5;++kk) { pv[base+kk] = bv5[kk]; pi[base+kk] = bi5[kk]; }
    }
}

// ---------- K3b: merge the two column-half partials ----------
__global__ __launch_bounds__(256) void k_topkmerge(const float* __restrict__ pv, const int* __restrict__ pi,
                                                   int* __restrict__ idxo)
{
    int t = blockIdx.x*256 + threadIdx.x;   // 0..16383 = (b,n)
    float bv5[5]; int bi5[5];
    #pragma unroll
    for (int kk=0;kk<5;++kk){ bv5[kk]=-3.0e38f; bi5[kk]=0x7fffffff; }
    size_t base = (size_t)t*10;
    #pragma unroll
    for (int e=0;e<10;++e) ins5t(bv5,bi5, pv[base+e], pi[base+e]);
    #pragma unroll
    for (int kk=0;kk<5;++kk) idxo[(size_t)t*5+kk] = bi5[kk];
}

// ---------- K4: fused laplacian(k)·laplacian(v) partial reduction ----------
__global__ __launch_bounds__(256) void k_kv(const float* __restrict__ ko, const float* __restrict__ vo,
                                            const int* __restrict__ idxo, float* __restrict__ part)
{
    int blk = blockIdx.x;                 // bh(16) * chunk(16)
    int chunk = blk & 15, bh = blk >> 4, b = bh >> 2;
    int t = threadIdx.x;
    int f = t & 63, g = t >> 6;
    const float* kb = ko + (size_t)bh*NN*64;
    const float* vb = vo + (size_t)bh*NN*64;
    const int* ib = idxo + (size_t)b*NN*5;
    float acc = 0.f;
    int nbase = chunk*256 + g*64;
    for (int i2 = 0; i2 < 64; ++i2) {
        int n = nbase + i2;
        const int* ip = ib + (size_t)n*5;
        int j0 = ip[0], j1 = ip[1], j2 = ip[2], j3 = ip[3], j4 = ip[4];
        float lk = kb[(size_t)n*64+f] + kb[(size_t)j0*64+f] + kb[(size_t)j1*64+f]
                 + kb[(size_t)j2*64+f] + kb[(size_t)j3*64+f] + kb[(size_t)j4*64+f];
        float lv = vb[(size_t)n*64+f] + vb[(size_t)j0*64+f] + vb[(size_t)j1*64+f]
                 + vb[(size_t)j2*64+f] + vb[(size_t)j3*64+f] + vb[(size_t)j4*64+f];
        acc += lk*lv;
    }
    __shared__ float red[4][64];
    red[g][f] = acc;
    __syncthreads();
    if (t < 64) {
        float s2 = red[0][t] + red[1][t] + red[2][t] + red[3][t];
        part[((size_t)bh*64 + t)*16 + chunk] = s2;
    }
}

// ---------- K5: wps[b][o][hf] = wp[o][hf] * kv[b][hf] ----------
__global__ __launch_bounds__(256) void k_wps(const float* __restrict__ wp, const float* __restrict__ part,
                                             float* __restrict__ wps)
{
    int t = blockIdx.x*256 + threadIdx.x;    // 65536 = b(4)*o(64)*hf(256)
    int b = t >> 14, rem = t & 16383;
    int hf = rem & 255;
    const float* pp = part + ((size_t)b*256 + hf)*16;
    float s = 0.f;
    #pragma unroll
    for (int c2 = 0; c2 < 16; ++c2) s += pp[c2];
    wps[t] = wp[rem] * (s * (1.f/36.f));
}

// ---------- K6: fused (hy·wp) conv + conv1/BN/ReLU + conv2/BN/ReLU ----------
__global__ __launch_bounds__(256) void k_out(
    const float* __restrict__ qo, const float* __restrict__ wpsb, const float* __restrict__ bp,
    const float* __restrict__ w1, const float* __restrict__ b1,
    const float* __restrict__ w2, const float* __restrict__ b2,
    const float* __restrict__ g1, const float* __restrict__ be1,
    const float* __restrict__ m1, const float* __restrict__ v1,
    const float* __restrict__ g2, const float* __restrict__ be2,
    const float* __restrict__ m2, const float* __restrict__ v2,
    float* __restrict__ outp)
{
    int b  = blockIdx.x >> 6;
    int n0 = (blockIdx.x & 63)*64;
    __shared__ __align__(16) float qs[256*68];   // q tile [hf][nl]; later t1 [o][nl]
    __shared__ __align__(16) float ws2[256*68];  // wps [hf][o]; later w1s/w2s [c][o]
    __shared__ __align__(16) float t0[64*68];    // conv_p out [o][nl]; later t2
    int t = threadIdx.x;
    {
        int f = t & 63, sub = t >> 6;
        #pragma unroll
        for (int h = 0; h < 4; ++h) {
            const float* qb = qo + (((size_t)(b*4+h))*NN + n0)*64 + f;
            for (int nl = sub; nl < 64; nl += 4)
                qs[(h*64+f)*68 + nl] = qb[(size_t)nl*64];
        }
    }
    {
        const float* wb = wpsb + (size_t)b*64*256;
        for (int o = 0; o < 64; ++o)
            ws2[t*68 + o] = wb[(size_t)o*256 + t];
    }
    __syncthreads();
    int tr = t >> 4, tc = t & 15;
    float acc[4][4];
    #pragma unroll
    for (int i=0;i<4;++i) {
        float bb = bp[tr*4+i];
        #pragma unroll
        for (int j=0;j<4;++j) acc[i][j] = bb;
    }
    #pragma unroll 8
    for (int hf = 0; hf < 256; ++hf) {
        float4 a4 = *(const float4*)&ws2[hf*68 + tr*4];
        float4 b4 = *(const float4*)&qs[hf*68 + tc*4];
        float av[4]={a4.x,a4.y,a4.z,a4.w}, bvv[4]={b4.x,b4.y,b4.z,b4.w};
        #pragma unroll
        for (int i=0;i<4;++i)
            #pragma unroll
            for (int j=0;j<4;++j)
                acc[i][j] += av[i]*bvv[j];
    }
    #pragma unroll
    for (int i=0;i<4;++i)
        *(float4*)&t0[(tr*4+i)*68 + tc*4] = make_float4(acc[i][0],acc[i][1],acc[i][2],acc[i][3]);
    __syncthreads();
    #pragma unroll
    for (int s = 0; s < 16; ++s) {   // w1 transposed into ws2
        int e = t + 256*s;
        ws2[(e & 63)*68 + (e >> 6)] = w1[e];
    }
    __syncthreads();
    float acc2[4][4];
    #pragma unroll
    for (int i=0;i<4;++i)
        #pragma unroll
        for (int j=0;j<4;++j) acc2[i][j] = 0.f;
    #pragma unroll 8
    for (int c = 0; c < 64; ++c) {
        float4 a4 = *(const float4*)&ws2[c*68 + tr*4];
        float4 b4 = *(const float4*)&t0[c*68 + tc*4];
        float av[4]={a4.x,a4.y,a4.z,a4.w}, bvv[4]={b4.x,b4.y,b4.z,b4.w};
        #pragma unroll
        for (int i=0;i<4;++i)
            #pragma unroll
            for (int j=0;j<4;++j)
                acc2[i][j] += av[i]*bvv[j];
    }
    #pragma unroll
    for (int i=0;i<4;++i) {          // BN1 + ReLU -> t1 (in qs region)
        int o = tr*4+i;
        float sc = g1[o] / sqrtf(v1[o] + 1e-5f);
        float bb = b1[o], mm = m1[o], bt = be1[o];
        float4 r;
        r.x = fmaxf((acc2[i][0]+bb-mm)*sc + bt, 0.f);
        r.y = fmaxf((acc2[i][1]+bb-mm)*sc + bt, 0.f);
        r.z = fmaxf((acc2[i][2]+bb-mm)*sc + bt, 0.f);
        r.w = fmaxf((acc2[i][3]+bb-mm)*sc + bt, 0.f);
        *(float4*)&qs[o*68 + tc*4] = r;
    }
    __syncthreads();
    #pragma unroll
    for (int s = 0; s < 16; ++s) {   // w2 transposed into ws2
        int e = t + 256*s;
        ws2[(e & 63)*68 + (e >> 6)] = w2[e];
    }
    __syncthreads();
    float acc3[4][4];
    #pragma unroll
    for (int i=0;i<4;++i)
        #pragma unroll
        for (int j=0;j<4;++j) acc3[i][j] = 0.f;
    #pragma unroll 8
    for (int c = 0; c < 64; ++c) {
        float4 a4 = *(const float4*)&ws2[c*68 + tr*4];
        float4 b4 = *(const float4*)&qs[c*68 + tc*4];
        float av[4]={a4.x,a4.y,a4.z,a4.w}, bvv[4]={b4.x,b4.y,b4.z,b4.w};
        #pragma unroll
        for (int i=0;i<4;++i)
            #pragma unroll
            for (int j=0;j<4;++j)
                acc3[i][j] += av[i]*bvv[j];
    }
    #pragma unroll
    for (int i=0;i<4;++i) {          // BN2 + ReLU -> t2 (in t0 region)
        int o = tr*4+i;
        float sc = g2[o] / sqrtf(v2[o] + 1e-5f);
        float bb = b2[o], mm = m2[o], bt = be2[o];
        float4 r;
        r.x = fmaxf((acc3[i][0]+bb-mm)*sc + bt, 0.f);
        r.y = fmaxf((acc3[i][1]+bb-mm)*sc + bt, 0.f);
        r.z = fmaxf((acc3[i][2]+bb-mm)*sc + bt, 0.f);
        r.w = fmaxf((acc3[i][3]+bb-mm)*sc + bt, 0.f);
        *(float4*)&t0[o*68 + tc*4] = r;
    }
    __syncthreads();
    float* ob = outp + ((size_t)b*64)*NN + n0;
    #pragma unroll
    for (int s = 0; s < 16; ++s) {
        int e = t + 256*s;
        int o = e >> 6, nl = e & 63;
        ob[(size_t)o*NN + nl] = t0[o*68 + nl];
    }
}

extern "C" void kernel_launch(void* const* d_in, const int* in_sizes, int n_in,
                              void* d_out, int out_size, void* d_ws, size_t ws_size,
                              hipStream_t stream)
{
    (void)in_sizes; (void)n_in; (void)out_size; (void)ws_size;
    const float* x  = (const float*)d_in[0];
    const float* wk = (const float*)d_in[1];
    const float* bk = (const float*)d_in[2];
    const float* wq = (const float*)d_in[3];
    const float* bq = (const float*)d_in[4];
    const float* wv = (const float*)d_in[5];
    const float* bv = (const float*)d_in[6];
    const float* wp = (const float*)d_in[7];
    const float* bp = (const float*)d_in[8];
    const float* w1 = (const float*)d_in[9];
    const float* b1 = (const float*)d_in[10];
    const float* w2 = (const float*)d_in[11];
    const float* b2 = (const float*)d_in[12];
    const float* g1 = (const float*)d_in[13];
    const float* be1= (const float*)d_in[14];
    const float* m1 = (const float*)d_in[15];
    const float* v1 = (const float*)d_in[16];
    const float* g2 = (const float*)d_in[17];
    const float* be2= (const float*)d_in[18];
    const float* m2 = (const float*)d_in[19];
    const float* v2 = (const float*)d_in[20];
    float* out = (float*)d_out;

    float* ws = (float*)d_ws;
    float* xn   = ws;  ws += (size_t)NB*NC*NN;        // 1,048,576
    float* qbuf = ws;  ws += (size_t)NB*NH*NN*64;     // 4,194,304
    float* kbuf = ws;  ws += (size_t)NB*NH*NN*64;
    float* vbuf = ws;  ws += (size_t)NB*NH*NN*64;
    float* wps  = ws;  ws += (size_t)NB*64*256;       // 65,536
    float* part = ws;  ws += (size_t)16*64*16;        // 16,384
    float* pv   = ws;  ws += (size_t)NB*NN*10;        // 163,840
    int*   pi   = (int*)ws;   ws += (size_t)NB*NN*10;
    int*   idxb = (int*)ws;   ws += (size_t)NB*NN*5;

    k_xnorm<<<64, 256, 0, stream>>>(x, xn);
    k_qkv<<<3072, 256, 0, stream>>>(x, wk,bk, wq,bq, wv,bv, qbuf,kbuf,vbuf);
    k_l2norm<<<512, 256, 0, stream>>>(qbuf, kbuf);
    k_topk<<<256, 256, 0, stream>>>(xn, pv, pi);
    k_topkmerge<<<64, 256, 0, stream>>>(pv, pi, idxb);
    k_kv<<<256, 256, 0, stream>>>(kbuf, vbuf, idxb, part);
    k_wps<<<256, 256, 0, stream>>>(wp, part, wps);
    k_out<<<256, 256, 0, stream>>>(qbuf, wps, bp, w1,b1, w2,b2,
                                   g1,be1,m1,v1, g2,be2,m2,v2, out);
}